// Round 12
// baseline (176.817 us; speedup 1.0000x reference)
//
#include <hip/hip_runtime.h>

// MoE B=4096, D=256, H=1024, E=8. 2 launches:
//  K1 prep (1288 blocks): 0..7 bin (first); 8..263 x->xb bf16 (block 8 zeroes done[]);
//     264..775 W1->w1t[e][h][d] bf16; 776..1287 W2->w2t[e][d][h] bf16.
//  K2 mlp (2048 blocks): R10 gemm1 body per (e,tile,hch) -> hw; then per-tile
//     completion counter (device-scope acq_rel). The 16th finisher block for a tile
//     acquires and runs the full R10 gemm2 body for that tile (4 n-chunks).
//     No grid sync, no extra launch; gemm2 overlaps gemm1's tail.

#define D_DIM 256
#define H_DIM 1024
#define E_NUM 8
#define B_TOK 4096
#define CAP   1024

typedef __attribute__((ext_vector_type(8))) short short8;
typedef __attribute__((ext_vector_type(4))) float f32x4;
typedef unsigned short u16;
typedef unsigned int u32;
typedef unsigned long long u64;

// ws layout (bytes)
#define CNT_OFF    0
#define BUCKET_OFF 1024
#define XB_OFF     (BUCKET_OFF + E_NUM*B_TOK*4)
#define W1T_OFF    (XB_OFF  + (size_t)B_TOK*D_DIM*2)
#define W2T_OFF    (W1T_OFF + (size_t)E_NUM*H_DIM*D_DIM*2)
#define HW_OFF     (W2T_OFF + (size_t)E_NUM*D_DIM*H_DIM*2)
#define DONE_OFF   (HW_OFF  + (size_t)E_NUM*CAP*H_DIM*2)

__device__ __forceinline__ u16 f2bf(float f) {
    u32 u = __builtin_bit_cast(u32, f);
    u = (u + 0x7fffu + ((u >> 16) & 1u)) >> 16;  // RNE
    return (u16)u;
}

__device__ __forceinline__ void trans_load(const float* __restrict__ in, int C,
                                           int rt, int ct, int tt, u16* tile) {
    #pragma unroll
    for (int it = 0; it < 4; ++it) {
        int r = it * 16 + (tt >> 4);
        int c4 = (tt & 15) * 4;
        float4 v = *(const float4*)(in + (size_t)(rt * 64 + r) * C + ct * 64 + c4);
        u64 pk = (u64)f2bf(v.x) | ((u64)f2bf(v.y) << 16)
               | ((u64)f2bf(v.z) << 32) | ((u64)f2bf(v.w) << 48);
        *(u64*)&tile[r * 68 + c4] = pk;
    }
}

__device__ __forceinline__ uint4 trans_pack(const u16* tile, int oc, int r0) {
    u32 p0 = tile[(r0 + 0) * 68 + oc] | ((u32)tile[(r0 + 1) * 68 + oc] << 16);
    u32 p1 = tile[(r0 + 2) * 68 + oc] | ((u32)tile[(r0 + 3) * 68 + oc] << 16);
    u32 p2 = tile[(r0 + 4) * 68 + oc] | ((u32)tile[(r0 + 5) * 68 + oc] << 16);
    u32 p3 = tile[(r0 + 6) * 68 + oc] | ((u32)tile[(r0 + 7) * 68 + oc] << 16);
    return uint4{p0, p1, p2, p3};
}

// ---- K1: prep = bin (first) | x convert (+done zero) | W1 trans | W2 trans ----
__global__ __launch_bounds__(256) void prep_kernel(
    const float* __restrict__ x, const float* __restrict__ W1,
    const float* __restrict__ W2, const int* __restrict__ eidx,
    int* __restrict__ cnt, int* __restrict__ bucket,
    u16* __restrict__ xb, u16* __restrict__ w1t, u16* __restrict__ w2t,
    int* __restrict__ done)
{
    __shared__ u16 tile[64 * 68];
    const int b = blockIdx.x, tid = threadIdx.x;
    if (b < 8) {                         // bin: block per expert, deterministic scan
        __shared__ int wsum[4];
        const int e = b;
        const int lane = tid & 63, wv = tid >> 6;
        int base = 0;
        #pragma unroll
        for (int c = 0; c < 16; ++c) {
            int t = c * 256 + tid;
            bool m = (eidx[t] == e);
            u64 bal = __ballot(m);
            int pfx = __popcll(bal & ((1ull << lane) - 1ull));
            if (lane == 0) wsum[wv] = __popcll(bal);
            __syncthreads();
            int wb = 0, total = 0;
            #pragma unroll
            for (int i = 0; i < 4; ++i) { if (i < wv) wb += wsum[i]; total += wsum[i]; }
            if (m) bucket[e * B_TOK + base + wb + pfx] = t;
            base += total;
            __syncthreads();
        }
        if (tid == 0) cnt[e] = base;
    } else if (b < 264) {                // x fp32 -> xb bf16 (block 8 zeroes done[])
        if (b == 8 && tid < 128) done[tid] = 0;
        int gb = b - 8;
        int row = gb * 16 + (tid >> 4);
        int sub = tid & 15;
        const float* src = x + (size_t)row * D_DIM + sub * 16;
        u16* dst = xb + (size_t)row * D_DIM + sub * 16;
        #pragma unroll
        for (int i = 0; i < 4; ++i) {
            float4 v = *(const float4*)(src + i * 4);
            u64 pk = (u64)f2bf(v.x) | ((u64)f2bf(v.y) << 16)
                   | ((u64)f2bf(v.z) << 32) | ((u64)f2bf(v.w) << 48);
            *(u64*)(dst + i * 4) = pk;
        }
    } else if (b < 776) {                // W1 [256d][1024h] -> w1t[e][h][d]
        int bb = b - 264;
        int e = bb >> 6, tj = bb & 63;
        int rt = tj >> 4, ct = tj & 15;
        trans_load(W1 + (size_t)e * D_DIM * H_DIM, H_DIM, rt, ct, tid, tile);
        __syncthreads();
        u16* outp = w1t + (size_t)e * H_DIM * D_DIM;
        #pragma unroll
        for (int it = 0; it < 2; ++it) {
            int oc = it * 32 + (tid >> 3);
            int r0 = (tid & 7) * 8;
            *(uint4*)(outp + (size_t)(ct * 64 + oc) * D_DIM + rt * 64 + r0) =
                trans_pack(tile, oc, r0);
        }
    } else {                             // W2 [1024h][256d] -> w2t[e][d][h]
        int bb = b - 776;
        int e = bb >> 6, tj = bb & 63;
        int rt = tj >> 2, ct = tj & 3;
        trans_load(W2 + (size_t)e * H_DIM * D_DIM, D_DIM, rt, ct, tid, tile);
        __syncthreads();
        u16* outp = w2t + (size_t)e * D_DIM * H_DIM;
        #pragma unroll
        for (int it = 0; it < 2; ++it) {
            int oc = it * 32 + (tid >> 3);
            int r0 = (tid & 7) * 8;
            *(uint4*)(outp + (size_t)(ct * 64 + oc) * H_DIM + rt * 64 + r0) =
                trans_pack(tile, oc, r0);
        }
    }
}

// ---- K2: gemm1 per (e,tile,hch); tile's 16th finisher runs gemm2 for the tile ----
__global__ __launch_bounds__(256, 2) void mlp_kernel(
    const u16* __restrict__ xb, const u16* __restrict__ w1t,
    const u16* __restrict__ w2t, const float* __restrict__ b1,
    const float* __restrict__ b2, const int* __restrict__ cnt,
    const int* __restrict__ bucket, u16* __restrict__ hw,
    int* __restrict__ done, float* __restrict__ out)
{
    __shared__ u16 xs[64 * 264];    // gemm2 reuses as as_
    __shared__ u16 w1s[64 * 264];   // gemm2 reuses as bs
    __shared__ u16 hs[64 * 72];
    __shared__ int isLast;

    const int b = blockIdx.x;
    const int e = b >> 8, tile = (b >> 4) & 15, hch = b & 15;
    const int n = min(cnt[e], CAP);
    const int row0 = tile * 64;
    if (row0 >= n) return;

    const int tid = threadIdx.x;
    const int w = tid >> 6, L = tid & 63, l15 = L & 15, l4 = L >> 4;
    const int wr = (w >> 1) * 32, wc = (w & 1) * 32;

    // ======== gemm1 (R10 body) ========
    {
        const int rr = tid >> 5, cc = (tid & 31) * 8;
        int tok[8];
        #pragma unroll
        for (int it = 0; it < 8; ++it) {
            int grow = row0 + it * 8 + rr;
            tok[it] = grow < n ? bucket[e * B_TOK + grow] : 0;
        }
        const u16* gw = w1t + ((size_t)e * H_DIM + hch * 64) * D_DIM;
        #pragma unroll
        for (int it = 0; it < 8; ++it) {
            int row = it * 8 + rr;
            *(short8*)&xs[row * 264 + cc]  = *(const short8*)&xb[(size_t)tok[it] * D_DIM + cc];
            *(short8*)&w1s[row * 264 + cc] = *(const short8*)&gw[(size_t)row * D_DIM + cc];
        }
    }
    __syncthreads();

    {
        f32x4 acc[2][2];
        #pragma unroll
        for (int i = 0; i < 2; ++i)
            #pragma unroll
            for (int j = 0; j < 2; ++j) acc[i][j] = (f32x4){0.f, 0.f, 0.f, 0.f};

        #pragma unroll
        for (int k = 0; k < 8; ++k) {
            short8 a0 = *(const short8*)&xs[(wr + l15) * 264 + k * 32 + l4 * 8];
            short8 a1 = *(const short8*)&xs[(wr + 16 + l15) * 264 + k * 32 + l4 * 8];
            short8 b0 = *(const short8*)&w1s[(wc + l15) * 264 + k * 32 + l4 * 8];
            short8 b1v = *(const short8*)&w1s[(wc + 16 + l15) * 264 + k * 32 + l4 * 8];
            acc[0][0] = __builtin_amdgcn_mfma_f32_16x16x32_bf16(a0, b0, acc[0][0], 0, 0, 0);
            acc[0][1] = __builtin_amdgcn_mfma_f32_16x16x32_bf16(a0, b1v, acc[0][1], 0, 0, 0);
            acc[1][0] = __builtin_amdgcn_mfma_f32_16x16x32_bf16(a1, b0, acc[1][0], 0, 0, 0);
            acc[1][1] = __builtin_amdgcn_mfma_f32_16x16x32_bf16(a1, b1v, acc[1][1], 0, 0, 0);
        }

        #pragma unroll
        for (int mr = 0; mr < 2; ++mr)
            #pragma unroll
            for (int nc = 0; nc < 2; ++nc) {
                float bias = b1[e * H_DIM + hch * 64 + wc + nc * 16 + l15];
                #pragma unroll
                for (int j = 0; j < 4; ++j) {
                    float v = fmaxf(acc[mr][nc][j] + bias, 0.f);
                    hs[(wr + mr * 16 + l4 * 4 + j) * 72 + wc + nc * 16 + l15] = f2bf(v);
                }
            }
    }
    __syncthreads();
    {
        u16* gh = hw + ((size_t)e * CAP + row0) * H_DIM + hch * 64;
        int rr8 = tid >> 3, off = (tid & 7) * 8;
        #pragma unroll
        for (int it = 0; it < 2; ++it) {
            int row = it * 32 + rr8;
            *(short8*)&gh[(size_t)row * H_DIM + off] = *(const short8*)&hs[row * 72 + off];
        }
    }

    // ======== completion counter (release/acquire, agent scope) ========
    __syncthreads();   // all hw stores retired (vmcnt drained before barrier)
    if (tid == 0) {
        __threadfence();   // release: prior block writes visible device-wide
        int old = __hip_atomic_fetch_add(&done[e * 16 + tile], 1,
                                         __ATOMIC_ACQ_REL, __HIP_MEMORY_SCOPE_AGENT);
        isLast = (old == 15);
    }
    __syncthreads();
    if (!isLast) return;
    __threadfence();       // acquire: invalidate stale cache before reading others' hw

    // ======== gemm2 for (e,tile): all 4 n-chunks (R10 body) ========
    const u16* ga = hw + ((size_t)e * CAP + row0) * H_DIM;
    for (int nch = 0; nch < 4; ++nch) {
        f32x4 acc[2][2];
        #pragma unroll
        for (int i = 0; i < 2; ++i)
            #pragma unroll
            for (int j = 0; j < 2; ++j) acc[i][j] = (f32x4){0.f, 0.f, 0.f, 0.f};

        const u16* gb = w2t + ((size_t)e * D_DIM + nch * 64) * H_DIM;

        for (int kc = 0; kc < 4; ++kc) {
            __syncthreads();
            int rr = tid >> 5, cc = (tid & 31) * 8;
            #pragma unroll
            for (int it = 0; it < 8; ++it) {
                int row = it * 8 + rr;
                *(short8*)&xs[row * 264 + cc]  = *(const short8*)&ga[(size_t)row * H_DIM + kc * 256 + cc];
                *(short8*)&w1s[row * 264 + cc] = *(const short8*)&gb[(size_t)row * H_DIM + kc * 256 + cc];
            }
            __syncthreads();
            #pragma unroll
            for (int k = 0; k < 8; ++k) {
                short8 a0 = *(const short8*)&xs[(wr + l15) * 264 + k * 32 + l4 * 8];
                short8 a1 = *(const short8*)&xs[(wr + 16 + l15) * 264 + k * 32 + l4 * 8];
                short8 b0 = *(const short8*)&w1s[(wc + l15) * 264 + k * 32 + l4 * 8];
                short8 b1v = *(const short8*)&w1s[(wc + 16 + l15) * 264 + k * 32 + l4 * 8];
                acc[0][0] = __builtin_amdgcn_mfma_f32_16x16x32_bf16(a0, b0, acc[0][0], 0, 0, 0);
                acc[0][1] = __builtin_amdgcn_mfma_f32_16x16x32_bf16(a0, b1v, acc[0][1], 0, 0, 0);
                acc[1][0] = __builtin_amdgcn_mfma_f32_16x16x32_bf16(a1, b0, acc[1][0], 0, 0, 0);
                acc[1][1] = __builtin_amdgcn_mfma_f32_16x16x32_bf16(a1, b1v, acc[1][1], 0, 0, 0);
            }
        }

        #pragma unroll
        for (int mr = 0; mr < 2; ++mr)
            #pragma unroll
            for (int jj = 0; jj < 4; ++jj) {
                int m = wr + mr * 16 + l4 * 4 + jj;
                if (row0 + m < n) {
                    int token = bucket[e * B_TOK + row0 + m];
                    #pragma unroll
                    for (int nc = 0; nc < 2; ++nc) {
                        int d = nch * 64 + wc + nc * 16 + l15;
                        out[(size_t)token * D_DIM + d] = acc[mr][nc][jj] + b2[e * D_DIM + d];
                    }
                }
            }
        __syncthreads();   // scatter reads of xs/w1s done? (none) — orders next nch staging
    }
}

extern "C" void kernel_launch(void* const* d_in, const int* in_sizes, int n_in,
                              void* d_out, int out_size, void* d_ws, size_t ws_size,
                              hipStream_t stream) {
    const float* x  = (const float*)d_in[0];
    const float* W1 = (const float*)d_in[1];
    const float* b1 = (const float*)d_in[2];
    const float* W2 = (const float*)d_in[3];
    const float* b2 = (const float*)d_in[4];
    const int* eidx = (const int*)d_in[5];
    float* out = (float*)d_out;

    char* ws = (char*)d_ws;
    int* cnt    = (int*)(ws + CNT_OFF);
    int* bucket = (int*)(ws + BUCKET_OFF);
    u16* xb     = (u16*)(ws + XB_OFF);
    u16* w1t    = (u16*)(ws + W1T_OFF);
    u16* w2t    = (u16*)(ws + W2T_OFF);
    u16* hw     = (u16*)(ws + HW_OFF);
    int* done   = (int*)(ws + DONE_OFF);

    prep_kernel<<<1288, 256, 0, stream>>>(x, W1, W2, eidx, cnt, bucket, xb, w1t, w2t, done);
    mlp_kernel<<<E_NUM * 16 * 16, 256, 0, stream>>>(xb, w1t, w2t, b1, b2, cnt, bucket,
                                                    hw, done, out);
}

// Round 13
// 60.645 us; speedup vs baseline: 2.9156x; 2.9156x over previous
//
#include <hip/hip_runtime.h>

// MoE B=4096, D=256, H=1024, E=8. 3 launches:
//  K1 prep (1288 blocks): 0..7 bin; 8..263 x->xb bf16; 264..775 W1->w1t[e][h][d];
//     776..1287 W2->w2t[e][d][h].  (R10-proven)
//  K2 g1 (2048 x 64thr): LDS-FREE gemm1. One wave = 64x64 output tile (e,mt,hch).
//     A/B MFMA frags loaded DIRECT from L2 (16B/lane contiguous, pre-transposed
//     layout). relu+bias, repack via 8.7KB wave-private LDS, coalesced hw store.
//  K3 g2 (512 x 64thr): zero-LDS gemm2. One wave = 64x64 tile (e,mt,nch), K=1024
//     streamed as direct frags; scatter epilogue via bucket.

#define D_DIM 256
#define H_DIM 1024
#define E_NUM 8
#define B_TOK 4096
#define CAP   1024

typedef __attribute__((ext_vector_type(8))) short short8;
typedef __attribute__((ext_vector_type(4))) float f32x4;
typedef unsigned short u16;
typedef unsigned int u32;
typedef unsigned long long u64;

// ws layout (bytes)
#define CNT_OFF    0
#define BUCKET_OFF 1024
#define XB_OFF     (BUCKET_OFF + E_NUM*B_TOK*4)
#define W1T_OFF    (XB_OFF  + (size_t)B_TOK*D_DIM*2)
#define W2T_OFF    (W1T_OFF + (size_t)E_NUM*H_DIM*D_DIM*2)
#define HW_OFF     (W2T_OFF + (size_t)E_NUM*D_DIM*H_DIM*2)

__device__ __forceinline__ u16 f2bf(float f) {
    u32 u = __builtin_bit_cast(u32, f);
    u = (u + 0x7fffu + ((u >> 16) & 1u)) >> 16;  // RNE
    return (u16)u;
}

__device__ __forceinline__ void trans_load(const float* __restrict__ in, int C,
                                           int rt, int ct, int tt, u16* tile) {
    #pragma unroll
    for (int it = 0; it < 4; ++it) {
        int r = it * 16 + (tt >> 4);
        int c4 = (tt & 15) * 4;
        float4 v = *(const float4*)(in + (size_t)(rt * 64 + r) * C + ct * 64 + c4);
        u64 pk = (u64)f2bf(v.x) | ((u64)f2bf(v.y) << 16)
               | ((u64)f2bf(v.z) << 32) | ((u64)f2bf(v.w) << 48);
        *(u64*)&tile[r * 68 + c4] = pk;
    }
}

__device__ __forceinline__ uint4 trans_pack(const u16* tile, int oc, int r0) {
    u32 p0 = tile[(r0 + 0) * 68 + oc] | ((u32)tile[(r0 + 1) * 68 + oc] << 16);
    u32 p1 = tile[(r0 + 2) * 68 + oc] | ((u32)tile[(r0 + 3) * 68 + oc] << 16);
    u32 p2 = tile[(r0 + 4) * 68 + oc] | ((u32)tile[(r0 + 5) * 68 + oc] << 16);
    u32 p3 = tile[(r0 + 6) * 68 + oc] | ((u32)tile[(r0 + 7) * 68 + oc] << 16);
    return uint4{p0, p1, p2, p3};
}

// ---- K1: prep = bin | x convert | W1 trans | W2 trans (R10-proven) ----
__global__ __launch_bounds__(256) void prep_kernel(
    const float* __restrict__ x, const float* __restrict__ W1,
    const float* __restrict__ W2, const int* __restrict__ eidx,
    int* __restrict__ cnt, int* __restrict__ bucket,
    u16* __restrict__ xb, u16* __restrict__ w1t, u16* __restrict__ w2t)
{
    __shared__ u16 tile[64 * 68];
    const int b = blockIdx.x, tid = threadIdx.x;
    if (b < 8) {
        __shared__ int wsum[4];
        const int e = b;
        const int lane = tid & 63, wv = tid >> 6;
        int base = 0;
        #pragma unroll
        for (int c = 0; c < 16; ++c) {
            int t = c * 256 + tid;
            bool m = (eidx[t] == e);
            u64 bal = __ballot(m);
            int pfx = __popcll(bal & ((1ull << lane) - 1ull));
            if (lane == 0) wsum[wv] = __popcll(bal);
            __syncthreads();
            int wb = 0, total = 0;
            #pragma unroll
            for (int i = 0; i < 4; ++i) { if (i < wv) wb += wsum[i]; total += wsum[i]; }
            if (m) bucket[e * B_TOK + base + wb + pfx] = t;
            base += total;
            __syncthreads();
        }
        if (tid == 0) cnt[e] = base;
    } else if (b < 264) {                // x fp32 -> xb bf16
        int gb = b - 8;
        int row = gb * 16 + (tid >> 4);
        int sub = tid & 15;
        const float* src = x + (size_t)row * D_DIM + sub * 16;
        u16* dst = xb + (size_t)row * D_DIM + sub * 16;
        #pragma unroll
        for (int i = 0; i < 4; ++i) {
            float4 v = *(const float4*)(src + i * 4);
            u64 pk = (u64)f2bf(v.x) | ((u64)f2bf(v.y) << 16)
                   | ((u64)f2bf(v.z) << 32) | ((u64)f2bf(v.w) << 48);
            *(u64*)(dst + i * 4) = pk;
        }
    } else if (b < 776) {                // W1 -> w1t[e][h][d]
        int bb = b - 264;
        int e = bb >> 6, tj = bb & 63;
        int rt = tj >> 4, ct = tj & 15;
        trans_load(W1 + (size_t)e * D_DIM * H_DIM, H_DIM, rt, ct, tid, tile);
        __syncthreads();
        u16* outp = w1t + (size_t)e * H_DIM * D_DIM;
        #pragma unroll
        for (int it = 0; it < 2; ++it) {
            int oc = it * 32 + (tid >> 3);
            int r0 = (tid & 7) * 8;
            *(uint4*)(outp + (size_t)(ct * 64 + oc) * D_DIM + rt * 64 + r0) =
                trans_pack(tile, oc, r0);
        }
    } else {                             // W2 -> w2t[e][d][h]
        int bb = b - 776;
        int e = bb >> 6, tj = bb & 63;
        int rt = tj >> 2, ct = tj & 3;
        trans_load(W2 + (size_t)e * H_DIM * D_DIM, D_DIM, rt, ct, tid, tile);
        __syncthreads();
        u16* outp = w2t + (size_t)e * D_DIM * H_DIM;
        #pragma unroll
        for (int it = 0; it < 2; ++it) {
            int oc = it * 32 + (tid >> 3);
            int r0 = (tid & 7) * 8;
            *(uint4*)(outp + (size_t)(ct * 64 + oc) * H_DIM + rt * 64 + r0) =
                trans_pack(tile, oc, r0);
        }
    }
}

// ---- K2: g1 — LDS-free gemm1, 1 wave = 64x64 tile ----
__global__ __launch_bounds__(64) void g1_kernel(
    const u16* __restrict__ xb, const u16* __restrict__ w1t,
    const float* __restrict__ b1, const int* __restrict__ cnt,
    const int* __restrict__ bucket, u16* __restrict__ hw)
{
    __shared__ u16 hs[64 * 68];     // 8704 B, wave-private repack buffer

    const int b = blockIdx.x;
    const int e = b >> 8, mt = (b >> 4) & 15, hch = b & 15;
    const int n = min(cnt[e], CAP);
    const int row0 = mt * 64;
    if (row0 >= n) return;

    const int L = threadIdx.x;
    const int l15 = L & 15, l4 = L >> 4;

    // token per A-frag row (lane l15 owns row mr*16+l15)
    const u16* Ap[4];
    #pragma unroll
    for (int mr = 0; mr < 4; ++mr) {
        int grow = row0 + mr * 16 + l15;
        int tok = grow < n ? bucket[e * B_TOK + grow] : 0;
        Ap[mr] = xb + (size_t)tok * D_DIM;
    }
    const u16* Bp = w1t + ((size_t)e * H_DIM + hch * 64) * D_DIM;

    f32x4 acc[4][4];
    #pragma unroll
    for (int i = 0; i < 4; ++i)
        #pragma unroll
        for (int j = 0; j < 4; ++j) acc[i][j] = (f32x4){0.f, 0.f, 0.f, 0.f};

    #pragma unroll
    for (int k = 0; k < 8; ++k) {
        const int koff = k * 32 + l4 * 8;
        short8 a0 = *(const short8*)(Ap[0] + koff);
        short8 a1 = *(const short8*)(Ap[1] + koff);
        short8 a2 = *(const short8*)(Ap[2] + koff);
        short8 a3 = *(const short8*)(Ap[3] + koff);
        #pragma unroll
        for (int nc = 0; nc < 4; ++nc) {
            short8 bf = *(const short8*)(Bp + (size_t)(nc * 16 + l15) * D_DIM + koff);
            acc[0][nc] = __builtin_amdgcn_mfma_f32_16x16x32_bf16(a0, bf, acc[0][nc], 0, 0, 0);
            acc[1][nc] = __builtin_amdgcn_mfma_f32_16x16x32_bf16(a1, bf, acc[1][nc], 0, 0, 0);
            acc[2][nc] = __builtin_amdgcn_mfma_f32_16x16x32_bf16(a2, bf, acc[2][nc], 0, 0, 0);
            acc[3][nc] = __builtin_amdgcn_mfma_f32_16x16x32_bf16(a3, bf, acc[3][nc], 0, 0, 0);
        }
    }

    // bias + relu -> hs (C-frag: row=l4*4+j, col=l15)
    #pragma unroll
    for (int nc = 0; nc < 4; ++nc) {
        float bias = b1[e * H_DIM + hch * 64 + nc * 16 + l15];
        #pragma unroll
        for (int mr = 0; mr < 4; ++mr)
            #pragma unroll
            for (int j = 0; j < 4; ++j) {
                float v = fmaxf(acc[mr][nc][j] + bias, 0.f);
                hs[(mr * 16 + l4 * 4 + j) * 68 + nc * 16 + l15] = f2bf(v);
            }
    }
    // single wave: DS in-order; compiler inserts lgkmcnt before reads
    #pragma unroll
    for (int it = 0; it < 8; ++it) {
        int row = it * 8 + (L >> 3);
        int i = L & 7;
        short8 v = *(const short8*)&hs[row * 68 + i * 8];
        *(short8*)(hw + ((size_t)e * CAP + row0 + row) * H_DIM + hch * 64 + i * 8) = v;
    }
}

// ---- K3: g2 — zero-LDS gemm2, 1 wave = 64x64 tile, K=1024 ----
__global__ __launch_bounds__(64) void g2_kernel(
    const u16* __restrict__ hw, const u16* __restrict__ w2t,
    const float* __restrict__ b2, const int* __restrict__ cnt,
    const int* __restrict__ bucket, float* __restrict__ out)
{
    const int b = blockIdx.x;
    const int e = b >> 6, mt = (b >> 2) & 15, nch = b & 3;
    const int n = min(cnt[e], CAP);
    const int row0 = mt * 64;
    if (row0 >= n) return;

    const int L = threadIdx.x;
    const int l15 = L & 15, l4 = L >> 4;

    const u16* Ab = hw + ((size_t)e * CAP + row0) * H_DIM;       // [64 rows][1024]
    const u16* Bb = w2t + ((size_t)e * D_DIM + nch * 64) * H_DIM; // [64 d-rows][1024]

    f32x4 acc[4][4];
    #pragma unroll
    for (int i = 0; i < 4; ++i)
        #pragma unroll
        for (int j = 0; j < 4; ++j) acc[i][j] = (f32x4){0.f, 0.f, 0.f, 0.f};

    #pragma unroll 2
    for (int k = 0; k < 32; ++k) {
        const int koff = k * 32 + l4 * 8;
        short8 a0 = *(const short8*)(Ab + (size_t)(l15)      * H_DIM + koff);
        short8 a1 = *(const short8*)(Ab + (size_t)(16 + l15) * H_DIM + koff);
        short8 a2 = *(const short8*)(Ab + (size_t)(32 + l15) * H_DIM + koff);
        short8 a3 = *(const short8*)(Ab + (size_t)(48 + l15) * H_DIM + koff);
        #pragma unroll
        for (int nc = 0; nc < 4; ++nc) {
            short8 bf = *(const short8*)(Bb + (size_t)(nc * 16 + l15) * H_DIM + koff);
            acc[0][nc] = __builtin_amdgcn_mfma_f32_16x16x32_bf16(a0, bf, acc[0][nc], 0, 0, 0);
            acc[1][nc] = __builtin_amdgcn_mfma_f32_16x16x32_bf16(a1, bf, acc[1][nc], 0, 0, 0);
            acc[2][nc] = __builtin_amdgcn_mfma_f32_16x16x32_bf16(a2, bf, acc[2][nc], 0, 0, 0);
            acc[3][nc] = __builtin_amdgcn_mfma_f32_16x16x32_bf16(a3, bf, acc[3][nc], 0, 0, 0);
        }
    }

    // scatter epilogue: out[token][d] = acc + b2
    #pragma unroll
    for (int mr = 0; mr < 4; ++mr)
        #pragma unroll
        for (int j = 0; j < 4; ++j) {
            int m = mr * 16 + l4 * 4 + j;
            if (row0 + m < n) {
                int token = bucket[e * B_TOK + row0 + m];
                #pragma unroll
                for (int nc = 0; nc < 4; ++nc) {
                    int d = nch * 64 + nc * 16 + l15;
                    out[(size_t)token * D_DIM + d] = acc[mr][nc][j] + b2[e * D_DIM + d];
                }
            }
        }
}

extern "C" void kernel_launch(void* const* d_in, const int* in_sizes, int n_in,
                              void* d_out, int out_size, void* d_ws, size_t ws_size,
                              hipStream_t stream) {
    const float* x  = (const float*)d_in[0];
    const float* W1 = (const float*)d_in[1];
    const float* b1 = (const float*)d_in[2];
    const float* W2 = (const float*)d_in[3];
    const float* b2 = (const float*)d_in[4];
    const int* eidx = (const int*)d_in[5];
    float* out = (float*)d_out;

    char* ws = (char*)d_ws;
    int* cnt    = (int*)(ws + CNT_OFF);
    int* bucket = (int*)(ws + BUCKET_OFF);
    u16* xb     = (u16*)(ws + XB_OFF);
    u16* w1t    = (u16*)(ws + W1T_OFF);
    u16* w2t    = (u16*)(ws + W2T_OFF);
    u16* hw     = (u16*)(ws + HW_OFF);

    prep_kernel<<<1288, 256, 0, stream>>>(x, W1, W2, eidx, cnt, bucket, xb, w1t, w2t);
    g1_kernel<<<E_NUM * 16 * 16, 64, 0, stream>>>(xb, w1t, b1, cnt, bucket, hw);
    g2_kernel<<<E_NUM * 16 * 4, 64, 0, stream>>>(hw, w2t, b2, cnt, bucket, out);
}